// Round 6
// baseline (273.148 us; speedup 1.0000x reference)
//
#include <hip/hip_runtime.h>
#include <hip/hip_bf16.h>
#include <cstdint>

#define N_SPK 1024
#define M_UTT 20
#define D_DIM 768
#define NM_ROWS (N_SPK * M_UTT)   // 20480 utterances / rows
#define NBLK 2560                 // gemm grid

static constexpr float EPS = 1e-8f;

typedef __attribute__((ext_vector_type(8))) short short8;   // 8 x bf16 (4 VGPRs)
typedef __attribute__((ext_vector_type(4))) float floatx4;  // MFMA accumulator

__device__ __forceinline__ void load16_to_lds(const void* g, void* l) {
    __builtin_amdgcn_global_load_lds(
        (const __attribute__((address_space(1))) uint32_t*)g,
        (__attribute__((address_space(3))) uint32_t*)l, 16, 0, 0);
}

__device__ __forceinline__ unsigned short bf16bits(float x) {
    __hip_bfloat16 h = __float2bfloat16(x);
    return *(unsigned short*)&h;
}

__device__ __forceinline__ float wave_sum(float v) {
    #pragma unroll
    for (int o = 32; o > 0; o >>= 1) v += __shfl_xor(v, o);
    return v;
}

// ---------------------------------------------------------------------------
// Kernel 1 (prep): per speaker, read emb once (float2/thread, 384 thr),
// centroid + 20 utterance norms, bf16 Chat/Ehat ([m][i][d]) ushort2 stores.
// Also zero-inits Ssum (20 slots/block) and ctr — replaces the memset node.
// ---------------------------------------------------------------------------
__global__ __launch_bounds__(384) void prep_kernel(const float* __restrict__ emb,
                                                   __hip_bfloat16* __restrict__ ehat,
                                                   __hip_bfloat16* __restrict__ chat,
                                                   float* __restrict__ Ssum,
                                                   int* __restrict__ ctr) {
    const int i = blockIdx.x;      // speaker
    const int t = threadIdx.x;     // 0..383
    const int wave = t >> 6, lane = t & 63;

    if (t < M_UTT) Ssum[i * M_UTT + t] = 0.f;   // covers all 20480
    if (i == 0 && t == M_UTT) *ctr = 0;

    const float2* src = (const float2*)(emb + (size_t)i * M_UTT * D_DIM);

    float2 v[M_UTT];
    float ss[M_UTT];
    float2 cen = {0.f, 0.f};
    #pragma unroll
    for (int m = 0; m < M_UTT; ++m) {
        const float2 x = src[m * 384 + t];
        v[m] = x;
        ss[m] = x.x * x.x + x.y * x.y;
        cen.x += x.x; cen.y += x.y;
    }
    cen.x *= (1.f / M_UTT); cen.y *= (1.f / M_UTT);
    float css = cen.x * cen.x + cen.y * cen.y;

    __shared__ float red[M_UTT + 1][6];
    #pragma unroll
    for (int m = 0; m < M_UTT; ++m) {
        const float s = wave_sum(ss[m]);
        if (lane == 0) red[m][wave] = s;
    }
    {
        const float s = wave_sum(css);
        if (lane == 0) red[M_UTT][wave] = s;
    }
    __syncthreads();

    #pragma unroll
    for (int m = 0; m < M_UTT; ++m) {
        const float tot = red[m][0] + red[m][1] + red[m][2] +
                          red[m][3] + red[m][4] + red[m][5];
        const float rn = 1.0f / fmaxf(sqrtf(tot), EPS);
        ushort2 o;
        o.x = bf16bits(v[m].x * rn); o.y = bf16bits(v[m].y * rn);
        *(ushort2*)((unsigned short*)ehat + ((size_t)(m * N_SPK + i)) * D_DIM + 2 * t) = o;
    }
    {
        const float tot = red[M_UTT][0] + red[M_UTT][1] + red[M_UTT][2] +
                          red[M_UTT][3] + red[M_UTT][4] + red[M_UTT][5];
        const float rn = 1.0f / fmaxf(sqrtf(tot), EPS);
        ushort2 o;
        o.x = bf16bits(cen.x * rn); o.y = bf16bits(cen.y * rn);
        *(ushort2*)((unsigned short*)chat + (size_t)i * D_DIM + 2 * t) = o;
    }
}

// ---------------------------------------------------------------------------
// Kernel 2: GEMM + fixed-offset softmax partials + last-block finalize.
// 128x64 tile, BK=64 (12 iters — half the barrier drains of R4), 2 waves,
// single-buffered LDS (R5's dbuf regressed). 4x4 MFMA 16x16x32 per wave
// per k-half.
// Fixed-offset softmax: logit = w*cos+b <= w+b, so partial = sum exp(w*(cos-1))
// needs NO max tracking -> per-column atomicAdd into global Ssum.
// Target sims via atomicExch. Device-scope ctr; block 2559 computes the loss
// (atomic reads for cross-XCD visibility). TWO dispatches total.
// LDS XOR swizzle: chunk q stored at slot qs = q ^ (row&7); fragment reads
// hit each bank exactly 2x (free per m136).
// ---------------------------------------------------------------------------
__global__ __launch_bounds__(128) void gemm_fused_kernel(
        const __hip_bfloat16* __restrict__ ehat,
        const __hip_bfloat16* __restrict__ chat,
        const float* __restrict__ wp,
        const float* __restrict__ bp,
        float* __restrict__ Ssum,
        float* __restrict__ T,
        int* __restrict__ ctr,
        float* __restrict__ out) {
    __shared__ __hip_bfloat16 As[128 * 64];   // 16 KB
    __shared__ __hip_bfloat16 Bs[64 * 64];    //  8 KB
    __shared__ float red[2][64];
    __shared__ int last_flag;

    const int t = threadIdx.x;          // 0..127
    const int lane = t & 63;
    const int wid = t >> 6;             // row half 0/1
    const int c = lane & 15;
    const int quad = lane >> 4;

    const int xcd = blockIdx.x & 7;
    const int idx = blockIdx.x >> 3;        // 0..319
    const int bu  = xcd * 20 + (idx >> 4);  // 0..159
    const int bj  = idx & 15;               // 0..15
    const int m   = bu >> 3;
    const int rb  = bu & 7;
    const int u0  = bu * 128;
    const int j0  = bj * 64;

    const short* Ag = (const short*)ehat + (size_t)u0 * D_DIM;
    const short* Bg = (const short*)chat + (size_t)j0 * D_DIM;

    floatx4 acc[4][4] = {};

    for (int k0 = 0; k0 < D_DIM; k0 += 64) {
        // stage A: 128 rows x 8 chunks(16B); thread t -> chunks ci = s*128+t
        #pragma unroll
        for (int s = 0; s < 8; ++s) {
            const int ci  = s * 128 + t;
            const int row = ci >> 3;
            const int q   = (ci & 7) ^ (row & 7);
            load16_to_lds(Ag + (size_t)row * D_DIM + k0 + q * 8, (short*)As + ci * 8);
        }
        // stage B: 64 rows x 8 chunks
        #pragma unroll
        for (int s = 0; s < 4; ++s) {
            const int ci  = s * 128 + t;
            const int row = ci >> 3;
            const int q   = (ci & 7) ^ (row & 7);
            load16_to_lds(Bg + (size_t)row * D_DIM + k0 + q * 8, (short*)Bs + ci * 8);
        }
        __syncthreads();

        #pragma unroll
        for (int kh = 0; kh < 2; ++kh) {
            short8 af[4], bf[4];
            #pragma unroll
            for (int it = 0; it < 4; ++it) {
                const int r = wid * 64 + it * 16 + c;
                const int slot = r * 8 + ((kh * 4 + quad) ^ (r & 7));
                af[it] = *(const short8*)((const short*)As + slot * 8);
            }
            #pragma unroll
            for (int jt = 0; jt < 4; ++jt) {
                const int r = jt * 16 + c;
                const int slot = r * 8 + ((kh * 4 + quad) ^ (r & 7));
                bf[jt] = *(const short8*)((const short*)Bs + slot * 8);
            }
            #pragma unroll
            for (int it = 0; it < 4; ++it)
                #pragma unroll
                for (int jt = 0; jt < 4; ++jt)
                    acc[it][jt] = __builtin_amdgcn_mfma_f32_16x16x32_bf16(af[it], bf[jt], acc[it][jt], 0, 0, 0);
        }
        __syncthreads();
    }

    const float w = wp[0], b = bp[0];

    // per-column fixed-offset partial: sum exp(w*(cos-1)) over wave's 64 rows
    #pragma unroll
    for (int jt = 0; jt < 4; ++jt) {
        float sm = 0.f;
        #pragma unroll
        for (int it = 0; it < 4; ++it)
            #pragma unroll
            for (int r = 0; r < 4; ++r)
                sm += __expf(w * (acc[it][jt][r] - 1.0f));
        sm += __shfl_xor(sm, 16);
        sm += __shfl_xor(sm, 32);
        if (quad == 0) red[wid][jt * 16 + c] = sm;
    }

    // target sims: row within m-slab == (m*1024+col)/20
    #pragma unroll
    for (int it = 0; it < 4; ++it) {
        #pragma unroll
        for (int jt = 0; jt < 4; ++jt) {
            const int col = j0 + jt * 16 + c;
            const int g = m * N_SPK + col;
            const int istar = g / M_UTT;
            const int rbase = rb * 128 + wid * 64 + it * 16 + quad * 4;
            #pragma unroll
            for (int r = 0; r < 4; ++r) {
                if (rbase + r == istar) atomicExch(&T[g], acc[it][jt][r]);
            }
        }
    }

    __syncthreads();
    if (wid == 0) {   // one atomicAdd per column (merged row halves)
        const int cc = lane;
        atomicAdd(&Ssum[m * N_SPK + j0 + cc], red[0][cc] + red[1][cc]);
    }

    // completion: last block computes the loss
    __threadfence();
    if (t == 0) {
        const int old = atomicAdd(ctr, 1);
        last_flag = (old == NBLK - 1) ? 1 : 0;
    }
    __syncthreads();
    if (last_flag) {
        // loss term per (m,j): w*(T-1) - log(Ssum)   [the (w+b) offsets cancel]
        float accl = 0.f;
        for (int p = t; p < NM_ROWS; p += 128) {
            const float Ss = atomicAdd(&Ssum[p], 0.0f);   // coherent reads
            const float Tv = atomicAdd(&T[p], 0.0f);
            accl += w * (Tv - 1.0f) - __logf(Ss);
        }
        red[0][t >> 1] = 0.f;  // (reuse LDS) -- init below instead
        __syncthreads();
        // block reduction via shuffles then LDS across the 2 waves
        float s = accl;
        #pragma unroll
        for (int o = 32; o > 0; o >>= 1) s += __shfl_xor(s, o);
        if (lane == 0) red[1][wid] = s;
        __syncthreads();
        if (t == 0) out[0] = -(red[1][0] + red[1][1]) / (float)NM_ROWS;
    }
}

// ---------------------------------------------------------------------------
extern "C" void kernel_launch(void* const* d_in, const int* in_sizes, int n_in,
                              void* d_out, int out_size, void* d_ws, size_t ws_size,
                              hipStream_t stream) {
    const float* emb = (const float*)d_in[0];
    const float* wp  = (const float*)d_in[1];
    const float* bp  = (const float*)d_in[2];
    float* out = (float*)d_out;

    char* ws = (char*)d_ws;
    //   Ehat bf16 [M][N][D] : 31,457,280  @ 0
    //   Chat bf16 [N][D]    :  1,572,864  @ 31,457,280
    //   Ssum f32 [M][N]     :     81,920  @ 33,030,144
    //   T    f32 [M][N]     :     81,920  @ 33,112,064
    //   ctr  i32            :          4  @ 33,193,984
    __hip_bfloat16* ehat = (__hip_bfloat16*)(ws);
    __hip_bfloat16* chat = (__hip_bfloat16*)(ws + 31457280);
    float* Ssum = (float*)(ws + 33030144);
    float* T    = (float*)(ws + 33112064);
    int*   ctr  = (int*)  (ws + 33193984);

    prep_kernel<<<dim3(N_SPK), dim3(384), 0, stream>>>(emb, ehat, chat, Ssum, ctr);
    gemm_fused_kernel<<<dim3(NBLK), dim3(128), 0, stream>>>(ehat, chat, wp, bp, Ssum, T, ctr, out);
}

// Round 7
// 161.119 us; speedup vs baseline: 1.6953x; 1.6953x over previous
//
#include <hip/hip_runtime.h>
#include <hip/hip_bf16.h>
#include <cstdint>

#define N_SPK 1024
#define M_UTT 20
#define D_DIM 768
#define NM_ROWS (N_SPK * M_UTT)   // 20480 utterances / rows

static constexpr float EPS = 1e-8f;

typedef __attribute__((ext_vector_type(8))) short short8;   // 8 x bf16 (4 VGPRs)
typedef __attribute__((ext_vector_type(4))) float floatx4;  // MFMA accumulator

__device__ __forceinline__ void load16_to_lds(const void* g, void* l) {
    __builtin_amdgcn_global_load_lds(
        (const __attribute__((address_space(1))) uint32_t*)g,
        (__attribute__((address_space(3))) uint32_t*)l, 16, 0, 0);
}

__device__ __forceinline__ unsigned short bf16bits(float x) {
    __hip_bfloat16 h = __float2bfloat16(x);
    return *(unsigned short*)&h;
}

__device__ __forceinline__ float wave_sum(float v) {
    #pragma unroll
    for (int o = 32; o > 0; o >>= 1) v += __shfl_xor(v, o);
    return v;
}

// ---------------------------------------------------------------------------
// Kernel 1 (prep): per speaker, read emb once (float2/thread, 384 thr),
// centroid + 20 utterance norms, bf16 Chat/Ehat ([m][i][d]) ushort2 stores.
// Also zero-inits ctr/accum (replaces a memset dispatch).
// ---------------------------------------------------------------------------
__global__ __launch_bounds__(384) void prep_kernel(const float* __restrict__ emb,
                                                   __hip_bfloat16* __restrict__ ehat,
                                                   __hip_bfloat16* __restrict__ chat,
                                                   int* __restrict__ ctr,
                                                   float* __restrict__ accum) {
    const int i = blockIdx.x;      // speaker
    const int t = threadIdx.x;     // 0..383
    const int wave = t >> 6, lane = t & 63;

    if (i == 0 && t == 0) { *ctr = 0; *accum = 0.f; }

    const float2* src = (const float2*)(emb + (size_t)i * M_UTT * D_DIM);

    float2 v[M_UTT];
    float ss[M_UTT];
    float2 cen = {0.f, 0.f};
    #pragma unroll
    for (int m = 0; m < M_UTT; ++m) {
        const float2 x = src[m * 384 + t];
        v[m] = x;
        ss[m] = x.x * x.x + x.y * x.y;
        cen.x += x.x; cen.y += x.y;
    }
    cen.x *= (1.f / M_UTT); cen.y *= (1.f / M_UTT);
    float css = cen.x * cen.x + cen.y * cen.y;

    __shared__ float red[M_UTT + 1][6];
    #pragma unroll
    for (int m = 0; m < M_UTT; ++m) {
        const float s = wave_sum(ss[m]);
        if (lane == 0) red[m][wave] = s;
    }
    {
        const float s = wave_sum(css);
        if (lane == 0) red[M_UTT][wave] = s;
    }
    __syncthreads();

    #pragma unroll
    for (int m = 0; m < M_UTT; ++m) {
        const float tot = red[m][0] + red[m][1] + red[m][2] +
                          red[m][3] + red[m][4] + red[m][5];
        const float rn = 1.0f / fmaxf(sqrtf(tot), EPS);
        ushort2 o;
        o.x = bf16bits(v[m].x * rn); o.y = bf16bits(v[m].y * rn);
        *(ushort2*)((unsigned short*)ehat + ((size_t)(m * N_SPK + i)) * D_DIM + 2 * t) = o;
    }
    {
        const float tot = red[M_UTT][0] + red[M_UTT][1] + red[M_UTT][2] +
                          red[M_UTT][3] + red[M_UTT][4] + red[M_UTT][5];
        const float rn = 1.0f / fmaxf(sqrtf(tot), EPS);
        ushort2 o;
        o.x = bf16bits(cen.x * rn); o.y = bf16bits(cen.y * rn);
        *(ushort2*)((unsigned short*)chat + (size_t)i * D_DIM + 2 * t) = o;
    }
}

// ---------------------------------------------------------------------------
// Kernel 2: GEMM + fixed-offset softmax partial epilogue.
// K-loop byte-identical to R4's 64.9 µs version: 128x64 tile, BK=32, 2 waves,
// single-buffered LDS, stage;barrier;compute;barrier. XCD swizzle + XOR LDS
// swizzle (0 conflicts measured).
// Epilogue (lighter than R4): logit = w*cos+b <= w+b, so the partial is just
// sum exp(w*(cos-1)) per column — no max tracking. One plain Psum store per
// (row-block, col); T via plain store (unique owner).
// ---------------------------------------------------------------------------
__global__ __launch_bounds__(128) void gemm_fused_kernel(
        const __hip_bfloat16* __restrict__ ehat,
        const __hip_bfloat16* __restrict__ chat,
        const float* __restrict__ wp,
        float* __restrict__ Psum,
        float* __restrict__ T) {
    __shared__ __hip_bfloat16 As[128 * 32];
    __shared__ __hip_bfloat16 Bs[64 * 32];
    __shared__ float red[2][64];

    const int t = threadIdx.x;          // 0..127
    const int lane = t & 63;
    const int wid = t >> 6;             // row half 0/1
    const int c = lane & 15;
    const int quad = lane >> 4;

    const int xcd = blockIdx.x & 7;
    const int idx = blockIdx.x >> 3;        // 0..319
    const int bu  = xcd * 20 + (idx >> 4);  // 0..159
    const int bj  = idx & 15;               // 0..15
    const int m   = bu >> 3;
    const int rb  = bu & 7;
    const int u0  = bu * 128;
    const int j0  = bj * 64;

    const short* Ag = (const short*)ehat + (size_t)u0 * D_DIM;
    const short* Bg = (const short*)chat + (size_t)j0 * D_DIM;

    floatx4 acc[4][4] = {};

    for (int k0 = 0; k0 < D_DIM; k0 += 32) {
        #pragma unroll
        for (int s = 0; s < 4; ++s) {          // A: 512 16B chunks
            const int ci  = s * 128 + t;
            const int row = ci >> 2;
            const int q   = (ci & 3) ^ ((row >> 1) & 3);
            load16_to_lds(Ag + (size_t)row * D_DIM + k0 + q * 8, (short*)As + ci * 8);
        }
        #pragma unroll
        for (int s = 0; s < 2; ++s) {          // B: 256 16B chunks
            const int ci  = s * 128 + t;
            const int row = ci >> 2;
            const int q   = (ci & 3) ^ ((row >> 1) & 3);
            load16_to_lds(Bg + (size_t)row * D_DIM + k0 + q * 8, (short*)Bs + ci * 8);
        }
        __syncthreads();

        short8 af[4], bf[4];
        #pragma unroll
        for (int it = 0; it < 4; ++it) {
            const int r = wid * 64 + it * 16 + c;
            const int slot = r * 4 + (quad ^ ((r >> 1) & 3));
            af[it] = *(const short8*)((const short*)As + slot * 8);
        }
        #pragma unroll
        for (int jt = 0; jt < 4; ++jt) {
            const int r = jt * 16 + c;
            const int slot = r * 4 + (quad ^ ((r >> 1) & 3));
            bf[jt] = *(const short8*)((const short*)Bs + slot * 8);
        }

        #pragma unroll
        for (int it = 0; it < 4; ++it)
            #pragma unroll
            for (int jt = 0; jt < 4; ++jt)
                acc[it][jt] = __builtin_amdgcn_mfma_f32_16x16x32_bf16(af[it], bf[jt], acc[it][jt], 0, 0, 0);
        __syncthreads();
    }

    const float w = wp[0];

    // per-column fixed-offset partial: sum exp(w*(cos-1)) over wave's 64 rows
    #pragma unroll
    for (int jt = 0; jt < 4; ++jt) {
        float sm = 0.f;
        #pragma unroll
        for (int it = 0; it < 4; ++it)
            #pragma unroll
            for (int r = 0; r < 4; ++r)
                sm += __expf(w * (acc[it][jt][r] - 1.0f));
        sm += __shfl_xor(sm, 16);
        sm += __shfl_xor(sm, 32);
        if (quad == 0) red[wid][jt * 16 + c] = sm;
    }

    // target sims: row within m-slab == (m*1024+col)/20 (unique owner -> store)
    #pragma unroll
    for (int it = 0; it < 4; ++it) {
        #pragma unroll
        for (int jt = 0; jt < 4; ++jt) {
            const int col = j0 + jt * 16 + c;
            const int g = m * N_SPK + col;
            const int istar = g / M_UTT;
            const int rbase = rb * 128 + wid * 64 + it * 16 + quad * 4;
            #pragma unroll
            for (int r = 0; r < 4; ++r) {
                if (rbase + r == istar) T[g] = acc[it][jt][r];
            }
        }
    }

    __syncthreads();
    if (wid == 0) {   // one plain store per column (merged row halves)
        const int cc = lane;
        Psum[(m * 8 + rb) * N_SPK + j0 + cc] = red[0][cc] + red[1][cc];
    }
}

// ---------------------------------------------------------------------------
// Kernel 3: combine 8 row-block partials per (m,j) -> loss term; block sum;
// last-block writes the output (ctr/accum zeroed by prep).
// term = (w*T+b) - ((w+b) + log S) = w*(T-1) - log S.
// ---------------------------------------------------------------------------
__global__ void combine_kernel(const float* __restrict__ Psum,
                               const float* __restrict__ T,
                               const float* __restrict__ wp,
                               int* __restrict__ ctr,
                               float* __restrict__ accum,
                               float* __restrict__ out) {
    const int p = blockIdx.x * 256 + threadIdx.x;
    const int m = p >> 10;
    const int j = p & 1023;
    const float w = wp[0];

    float S = 0.f;
    #pragma unroll
    for (int rb = 0; rb < 8; ++rb)
        S += Psum[(m * 8 + rb) * N_SPK + j];
    const float term = w * (T[p] - 1.0f) - __logf(S);

    __shared__ float red[256];
    red[threadIdx.x] = term;
    __syncthreads();
    for (int o = 128; o > 0; o >>= 1) {
        if (threadIdx.x < o) red[threadIdx.x] += red[threadIdx.x + o];
        __syncthreads();
    }
    if (threadIdx.x == 0) {
        atomicAdd(accum, red[0]);
        __threadfence();
        const int old = atomicAdd(ctr, 1);
        if (old == 79) {
            const float a = atomicAdd(accum, 0.0f);   // coherent read
            out[0] = -a / (float)NM_ROWS;
        }
    }
}

// ---------------------------------------------------------------------------
extern "C" void kernel_launch(void* const* d_in, const int* in_sizes, int n_in,
                              void* d_out, int out_size, void* d_ws, size_t ws_size,
                              hipStream_t stream) {
    const float* emb = (const float*)d_in[0];
    const float* wp  = (const float*)d_in[1];
    float* out = (float*)d_out;

    char* ws = (char*)d_ws;
    //   Ehat bf16 [M][N][D] : 31,457,280  @ 0
    //   Chat bf16 [N][D]    :  1,572,864  @ 31,457,280
    //   Psum f32 [160][N]   :    655,360  @ 33,030,144
    //   T    f32 [M][N]     :     81,920  @ 33,685,504
    //   ctr  i32 + accum f32:          8  @ 33,767,424
    __hip_bfloat16* ehat = (__hip_bfloat16*)(ws);
    __hip_bfloat16* chat = (__hip_bfloat16*)(ws + 31457280);
    float* Psum  = (float*)(ws + 33030144);
    float* T     = (float*)(ws + 33685504);
    int*   ctr   = (int*)  (ws + 33767424);
    float* accum = (float*)(ws + 33767428);

    prep_kernel<<<dim3(N_SPK), dim3(384), 0, stream>>>(emb, ehat, chat, ctr, accum);
    gemm_fused_kernel<<<dim3(2560), dim3(128), 0, stream>>>(ehat, chat, wp, Psum, T);
    combine_kernel<<<dim3(80), dim3(256), 0, stream>>>(Psum, T, wp, ctr, accum, out);
}